// Round 4
// 9459.586 us; speedup vs baseline: 1.4881x; 1.4881x over previous
//
#include <hip/hip_runtime.h>
#include <hip/hip_bf16.h>

// Model config
#define Lc 2
#define Hc 1024
#define NHc 16
#define HDc 64
#define FFc 4096
#define Ec 8
#define Kc 2
#define Vc 32000
#define Sc 2048
#define EPSc 1e-5f

#define TM 64
#define TN 64
#define TKK 32

// ---------------- embedding ----------------
__global__ __launch_bounds__(256) void k_embed(const int* __restrict__ idx,
    const float* __restrict__ tok, const float* __restrict__ pos,
    float* __restrict__ x) {
  int t = blockIdx.x;
  int id = idx[t];
  for (int i = threadIdx.x; i < Hc; i += 256)
    x[t * Hc + i] = tok[(size_t)id * Hc + i] + pos[t * Hc + i];
}

// ---------------- layernorm (row of 1024, block=256) ----------------
__global__ __launch_bounds__(256) void k_ln(const float* __restrict__ x,
    const float* __restrict__ g, const float* __restrict__ b,
    float* __restrict__ o) {
  int row = blockIdx.x;
  int tid = threadIdx.x;
  const float* xr = x + (size_t)row * Hc;
  float v[4];
  float s = 0.f;
#pragma unroll
  for (int i = 0; i < 4; i++) { v[i] = xr[tid + 256 * i]; s += v[i]; }
  __shared__ float red[256];
  red[tid] = s; __syncthreads();
  for (int st = 128; st > 0; st >>= 1) {
    if (tid < st) red[tid] += red[tid + st];
    __syncthreads();
  }
  float mu = red[0] * (1.0f / Hc);
  __syncthreads();
  float s2 = 0.f;
#pragma unroll
  for (int i = 0; i < 4; i++) { float d = v[i] - mu; s2 += d * d; }
  red[tid] = s2; __syncthreads();
  for (int st = 128; st > 0; st >>= 1) {
    if (tid < st) red[tid] += red[tid + st];
    __syncthreads();
  }
  float rs = rsqrtf(red[0] * (1.0f / Hc) + EPSc);
  float* orow = o + (size_t)row * Hc;
#pragma unroll
  for (int i = 0; i < 4; i++) {
    int c = tid + 256 * i;
    orow[c] = (v[i] - mu) * rs * g[c] + b[c];
  }
}

// ---------------- generic NT GEMM: C = A[M,K] @ B[N,K]^T (+bias)(+resid) ----------------
__global__ __launch_bounds__(256) void k_gemm_nt(
    const float* __restrict__ A, const float* __restrict__ B,
    const float* __restrict__ bias, const float* __restrict__ resid,
    float* __restrict__ C, int M, int N, int K) {
  __shared__ float As[TKK][TM + 4];
  __shared__ float Bs[TKK][TN + 4];
  int m0 = blockIdx.x * TM, n0 = blockIdx.y * TN;
  int tid = threadIdx.x;
  int tx = tid & 15, ty = tid >> 4;
  int lrow = tid >> 3, lk = (tid & 7) * 4;
  float acc[4][4] = {};
  for (int k0 = 0; k0 < K; k0 += TKK) {
#pragma unroll
    for (int p = 0; p < 2; p++) {
      int r = lrow + 32 * p;
      float4 av = *(const float4*)&A[(size_t)(m0 + r) * K + k0 + lk];
      As[lk + 0][r] = av.x; As[lk + 1][r] = av.y;
      As[lk + 2][r] = av.z; As[lk + 3][r] = av.w;
      float4 bv = *(const float4*)&B[(size_t)(n0 + r) * K + k0 + lk];
      Bs[lk + 0][r] = bv.x; Bs[lk + 1][r] = bv.y;
      Bs[lk + 2][r] = bv.z; Bs[lk + 3][r] = bv.w;
    }
    __syncthreads();
#pragma unroll
    for (int kk = 0; kk < TKK; kk++) {
      float4 a = *(const float4*)&As[kk][ty * 4];
      float4 b = *(const float4*)&Bs[kk][tx * 4];
      const float* ap = (const float*)&a;
      const float* bp = (const float*)&b;
#pragma unroll
      for (int i = 0; i < 4; i++)
#pragma unroll
        for (int j = 0; j < 4; j++) acc[i][j] = fmaf(ap[i], bp[j], acc[i][j]);
    }
    __syncthreads();
  }
#pragma unroll
  for (int i = 0; i < 4; i++) {
    int m = m0 + ty * 4 + i;
    float4 outv;
    float* op = (float*)&outv;
#pragma unroll
    for (int j = 0; j < 4; j++) {
      int n = n0 + tx * 4 + j;
      float v = acc[i][j];
      if (bias) v += bias[n];
      if (resid) v += resid[(size_t)m * N + n];
      op[j] = v;
    }
    *(float4*)&C[(size_t)m * N + n0 + tx * 4] = outv;
  }
}

// ---------------- tiled flash attention ----------------
// One block (256 thr) per (head, 64-query tile). Online softmax over 64-key
// tiles. Score tile and PV tile are register-blocked GEMMs (4x4 per thread).
__global__ __launch_bounds__(256) void k_attn_tile(const float* __restrict__ qkv,
                                                   float* __restrict__ ctx) {
  int qt = blockIdx.x, h = blockIdx.y;
  int q0 = qt * 64;
  int tid = threadIdx.x;
  int tx = tid & 15, ty = tid >> 4;

  __shared__ float Qs[64][68];   // Q^T: [d][q]
  __shared__ float KPs[64][68];  // K^T: [d][j], reused as P^T: [j][q]
  __shared__ float Vs[64][68];   // V:   [j][d]

  float oacc[4][4] = {};
  float m[4] = {-INFINITY, -INFINITY, -INFINITY, -INFINITY};
  float l[4] = {0.f, 0.f, 0.f, 0.f};

  int lr = tid >> 2;            // 0..63 (row within tile)
  int d0 = (tid & 3) * 16;      // 0,16,32,48

  // stage Q^T once (pre-scaled by 1/sqrt(HD))
  {
    const float* qbase = qkv + (size_t)(q0 + lr) * 3072 + h * 64 + d0;
#pragma unroll
    for (int c = 0; c < 4; ++c) {
      float4 qv = *(const float4*)(qbase + 4 * c);
      Qs[d0 + 4 * c + 0][lr] = qv.x * 0.125f;
      Qs[d0 + 4 * c + 1][lr] = qv.y * 0.125f;
      Qs[d0 + 4 * c + 2][lr] = qv.z * 0.125f;
      Qs[d0 + 4 * c + 3][lr] = qv.w * 0.125f;
    }
  }
  __syncthreads();

  for (int jt = 0; jt <= qt; ++jt) {
    int j0 = jt * 64;
    // stage K^T and V
    {
      const float* kbase = qkv + (size_t)(j0 + lr) * 3072 + 1024 + h * 64 + d0;
      const float* vbase = qkv + (size_t)(j0 + lr) * 3072 + 2048 + h * 64 + d0;
#pragma unroll
      for (int c = 0; c < 4; ++c) {
        float4 kv = *(const float4*)(kbase + 4 * c);
        KPs[d0 + 4 * c + 0][lr] = kv.x;
        KPs[d0 + 4 * c + 1][lr] = kv.y;
        KPs[d0 + 4 * c + 2][lr] = kv.z;
        KPs[d0 + 4 * c + 3][lr] = kv.w;
        *(float4*)&Vs[lr][d0 + 4 * c] = *(const float4*)(vbase + 4 * c);
      }
    }
    __syncthreads();

    // score tile: S = Q^T-contract-d K  -> sacc[q 4][j 4]
    float sacc[4][4] = {};
#pragma unroll 8
    for (int kk = 0; kk < 64; ++kk) {
      float4 a = *(const float4*)&Qs[kk][ty * 4];
      float4 b = *(const float4*)&KPs[kk][tx * 4];
      const float* ap = (const float*)&a;
      const float* bp = (const float*)&b;
#pragma unroll
      for (int i = 0; i < 4; ++i)
#pragma unroll
        for (int jj = 0; jj < 4; ++jj)
          sacc[i][jj] = fmaf(ap[i], bp[jj], sacc[i][jj]);
    }

    // causal mask on the diagonal tile
    if (jt == qt) {
#pragma unroll
      for (int i = 0; i < 4; ++i)
#pragma unroll
        for (int jj = 0; jj < 4; ++jj)
          if (tx * 4 + jj > ty * 4 + i) sacc[i][jj] = -INFINITY;
    }

    // online softmax: rows owned by the 16 tx-lanes of each ty group
#pragma unroll
    for (int i = 0; i < 4; ++i) {
      float rm = fmaxf(fmaxf(sacc[i][0], sacc[i][1]),
                       fmaxf(sacc[i][2], sacc[i][3]));
#pragma unroll
      for (int o = 8; o > 0; o >>= 1) rm = fmaxf(rm, __shfl_xor(rm, o, 64));
      float mnew = fmaxf(m[i], rm);
      float alpha = __expf(m[i] - mnew);
      float rs = 0.f;
#pragma unroll
      for (int jj = 0; jj < 4; ++jj) {
        float p = __expf(sacc[i][jj] - mnew);
        sacc[i][jj] = p;
        rs += p;
      }
#pragma unroll
      for (int o = 8; o > 0; o >>= 1) rs += __shfl_xor(rs, o, 64);
      l[i] = l[i] * alpha + rs;
      m[i] = mnew;
#pragma unroll
      for (int jj = 0; jj < 4; ++jj) oacc[i][jj] *= alpha;
    }

    __syncthreads();  // everyone done reading K^T
    // write P^T into the K buffer: P^T[j][q]
#pragma unroll
    for (int i = 0; i < 4; ++i)
#pragma unroll
      for (int jj = 0; jj < 4; ++jj)
        KPs[tx * 4 + jj][ty * 4 + i] = sacc[i][jj];
    __syncthreads();

    // PV tile: O += P^T-contract-j V -> oacc[q 4][d 4]
#pragma unroll 8
    for (int kk = 0; kk < 64; ++kk) {
      float4 a = *(const float4*)&KPs[kk][ty * 4];
      float4 b = *(const float4*)&Vs[kk][tx * 4];
      const float* ap = (const float*)&a;
      const float* bp = (const float*)&b;
#pragma unroll
      for (int i = 0; i < 4; ++i)
#pragma unroll
        for (int jj = 0; jj < 4; ++jj)
          oacc[i][jj] = fmaf(ap[i], bp[jj], oacc[i][jj]);
    }
    __syncthreads();  // done with P^T/V before next tile's stage
  }

  // epilogue: ctx[q, h*64 + d] = O / l
#pragma unroll
  for (int i = 0; i < 4; ++i) {
    float inv = 1.0f / l[i];
    float4 ov;
    ov.x = oacc[i][0] * inv;
    ov.y = oacc[i][1] * inv;
    ov.z = oacc[i][2] * inv;
    ov.w = oacc[i][3] * inv;
    *(float4*)&ctx[(size_t)(q0 + ty * 4 + i) * Hc + h * 64 + tx * 4] = ov;
  }
}

// ---------------- router: softmax over 8 experts + top-2 + counts ----------------
__global__ __launch_bounds__(256) void k_router(const float* __restrict__ xf,
    const float* __restrict__ rw, int* __restrict__ topi,
    float* __restrict__ topw, int* __restrict__ counts) {
  int t = blockIdx.x;
  int tid = threadIdx.x;
  int e = tid >> 5, l = tid & 31;
  const float* xr = xf + (size_t)t * Hc;
  const float* we = rw + (size_t)e * Hc;
  float s = 0.f;
  for (int hh = l; hh < Hc; hh += 32) s += xr[hh] * we[hh];
  __shared__ float red[256];
  red[tid] = s; __syncthreads();
  for (int st = 16; st > 0; st >>= 1) {
    if (l < st) red[tid] += red[tid + st];
    __syncthreads();
  }
  if (tid == 0) {
    float lg[Ec], pr[Ec];
    float mx = -INFINITY;
    for (int k = 0; k < Ec; k++) { lg[k] = red[k * 32]; mx = fmaxf(mx, lg[k]); }
    float ps = 0.f;
    for (int k = 0; k < Ec; k++) { pr[k] = expf(lg[k] - mx); ps += pr[k]; }
    float inv = 1.0f / ps;
    for (int k = 0; k < Ec; k++) pr[k] *= inv;
    int i1 = 0;
    for (int k = 1; k < Ec; k++) if (pr[k] > pr[i1]) i1 = k;
    int i2 = (i1 == 0) ? 1 : 0;
    for (int k = 0; k < Ec; k++)
      if (k != i1 && pr[k] > pr[i2]) i2 = k;
    topi[2 * t] = i1; topi[2 * t + 1] = i2;
    topw[2 * t] = pr[i1]; topw[2 * t + 1] = pr[i2];
    atomicAdd(&counts[i1], 1);
    atomicAdd(&counts[i2], 1);
  }
}

__global__ void k_offs(const int* __restrict__ counts, int* __restrict__ offs) {
  int acc = 0;
  for (int e = 0; e < Ec; e++) { offs[e] = acc; acc += counts[e]; }
}

__global__ __launch_bounds__(256) void k_scatter(const int* __restrict__ topi,
    const float* __restrict__ topw, const int* __restrict__ offs,
    int* __restrict__ cursor, int* __restrict__ elist,
    float* __restrict__ ecoef) {
  int t = blockIdx.x * 256 + threadIdx.x;
  if (t >= Sc) return;
#pragma unroll
  for (int s = 0; s < Kc; s++) {
    int e = topi[2 * t + s];
    int p = atomicAdd(&cursor[e], 1);
    int gslot = offs[e] + p;
    elist[gslot] = t;
    ecoef[gslot] = topw[2 * t + s];
  }
}

// ---------------- MoE GEMM1: h1[slot,f] = gelu(x[tok[slot],:] @ w1[e][:,f]) ----------------
__global__ __launch_bounds__(256) void k_moe_gemm1(
    const float* __restrict__ X, const float* __restrict__ W1,
    const int* __restrict__ elist, const int* __restrict__ counts,
    const int* __restrict__ offs, float* __restrict__ H1) {
  int e = blockIdx.z;
  int cnt = counts[e];
  int m0 = blockIdx.x * TM;
  if (m0 >= cnt) return;
  int n0 = blockIdx.y * TN;
  int off = offs[e];
  const float* B = W1 + (size_t)e * Hc * FFc;
  __shared__ float As[TKK][TM + 4];
  __shared__ float Bs[TKK][TN + 4];
  int tid = threadIdx.x, tx = tid & 15, ty = tid >> 4;
  int lrow = tid >> 3, lk = (tid & 7) * 4;
  int lk2 = tid >> 4, ln4 = (tid & 15) * 4;
  float acc[4][4] = {};
  for (int k0 = 0; k0 < Hc; k0 += TKK) {
#pragma unroll
    for (int p = 0; p < 2; p++) {
      int r = lrow + 32 * p;
      float4 av = make_float4(0.f, 0.f, 0.f, 0.f);
      if (m0 + r < cnt) {
        int tok = elist[off + m0 + r];
        av = *(const float4*)&X[(size_t)tok * Hc + k0 + lk];
      }
      As[lk + 0][r] = av.x; As[lk + 1][r] = av.y;
      As[lk + 2][r] = av.z; As[lk + 3][r] = av.w;
      int k = lk2 + 16 * p;
      *(float4*)&Bs[k][ln4] = *(const float4*)&B[(size_t)(k0 + k) * FFc + n0 + ln4];
    }
    __syncthreads();
#pragma unroll
    for (int kk = 0; kk < TKK; kk++) {
      float4 a = *(const float4*)&As[kk][ty * 4];
      float4 b = *(const float4*)&Bs[kk][tx * 4];
      const float* ap = (const float*)&a;
      const float* bp = (const float*)&b;
#pragma unroll
      for (int i = 0; i < 4; i++)
#pragma unroll
        for (int j = 0; j < 4; j++) acc[i][j] = fmaf(ap[i], bp[j], acc[i][j]);
    }
    __syncthreads();
  }
#pragma unroll
  for (int i = 0; i < 4; i++) {
    int r = m0 + ty * 4 + i;
    if (r < cnt) {
      float4 outv;
      float* op = (float*)&outv;
#pragma unroll
      for (int j = 0; j < 4; j++) {
        float xv = acc[i][j];
        op[j] = 0.5f * xv * (1.0f + erff(xv * 0.70710678118654752f));
      }
      *(float4*)&H1[(size_t)(off + r) * FFc + n0 + tx * 4] = outv;
    }
  }
}

// ---------------- MoE GEMM2: x[tok] += coef * (h1[slot,:] @ w2[e]) ----------------
__global__ __launch_bounds__(256) void k_moe_gemm2(
    const float* __restrict__ H1, const float* __restrict__ W2,
    const int* __restrict__ elist, const float* __restrict__ ecoef,
    const int* __restrict__ counts, const int* __restrict__ offs,
    float* __restrict__ X) {
  int e = blockIdx.z;
  int cnt = counts[e];
  int m0 = blockIdx.x * TM;
  if (m0 >= cnt) return;
  int n0 = blockIdx.y * TN;
  int off = offs[e];
  const float* A = H1 + (size_t)off * FFc;
  const float* B = W2 + (size_t)e * FFc * Hc;
  __shared__ float As[TKK][TM + 4];
  __shared__ float Bs[TKK][TN + 4];
  int tid = threadIdx.x, tx = tid & 15, ty = tid >> 4;
  int lrow = tid >> 3, lk = (tid & 7) * 4;
  int lk2 = tid >> 4, ln4 = (tid & 15) * 4;
  float acc[4][4] = {};
  for (int k0 = 0; k0 < FFc; k0 += TKK) {
#pragma unroll
    for (int p = 0; p < 2; p++) {
      int r = lrow + 32 * p;
      float4 av = make_float4(0.f, 0.f, 0.f, 0.f);
      if (m0 + r < cnt)
        av = *(const float4*)&A[(size_t)(m0 + r) * FFc + k0 + lk];
      As[lk + 0][r] = av.x; As[lk + 1][r] = av.y;
      As[lk + 2][r] = av.z; As[lk + 3][r] = av.w;
      int k = lk2 + 16 * p;
      *(float4*)&Bs[k][ln4] = *(const float4*)&B[(size_t)(k0 + k) * Hc + n0 + ln4];
    }
    __syncthreads();
#pragma unroll
    for (int kk = 0; kk < TKK; kk++) {
      float4 a = *(const float4*)&As[kk][ty * 4];
      float4 b = *(const float4*)&Bs[kk][tx * 4];
      const float* ap = (const float*)&a;
      const float* bp = (const float*)&b;
#pragma unroll
      for (int i = 0; i < 4; i++)
#pragma unroll
        for (int j = 0; j < 4; j++) acc[i][j] = fmaf(ap[i], bp[j], acc[i][j]);
    }
    __syncthreads();
  }
#pragma unroll
  for (int i = 0; i < 4; i++) {
    int r = m0 + ty * 4 + i;
    if (r < cnt) {
      int tok = elist[off + r];
      float cf = ecoef[off + r];
#pragma unroll
      for (int j = 0; j < 4; j++)
        atomicAdd(&X[(size_t)tok * Hc + n0 + tx * 4 + j], cf * acc[i][j]);
    }
  }
}

extern "C" void kernel_launch(void* const* d_in, const int* in_sizes, int n_in,
                              void* d_out, int out_size, void* d_ws, size_t ws_size,
                              hipStream_t stream) {
  const int*   idx   = (const int*)d_in[0];
  const float* tok   = (const float*)d_in[1];
  const float* pos   = (const float*)d_in[2];
  const float* ln1g  = (const float*)d_in[3];
  const float* ln1b  = (const float*)d_in[4];
  const float* wqkv  = (const float*)d_in[5];
  const float* bqkv  = (const float*)d_in[6];
  const float* wo    = (const float*)d_in[7];
  const float* bo    = (const float*)d_in[8];
  const float* ln2g  = (const float*)d_in[9];
  const float* ln2b  = (const float*)d_in[10];
  const float* rw    = (const float*)d_in[11];
  const float* w1    = (const float*)d_in[12];
  const float* w2    = (const float*)d_in[13];
  const float* lnfg  = (const float*)d_in[14];
  const float* lnfb  = (const float*)d_in[15];

  float* ws   = (float*)d_ws;
  float* x    = ws;                    // Sc*Hc
  float* lnb  = x + Sc * Hc;           // Sc*Hc
  float* qkv  = lnb + Sc * Hc;         // Sc*3*Hc
  float* ctx  = qkv + Sc * 3 * Hc;     // Sc*Hc
  float* topw  = ctx + Sc * Hc;        // Sc*Kc
  float* ecoef = topw + Sc * Kc;       // Sc*Kc
  int* topi    = (int*)(ecoef + Sc * Kc);  // Sc*Kc
  int* elist   = topi + Sc * Kc;           // Sc*Kc
  int* counts  = elist + Sc * Kc;          // Ec
  int* cursor  = counts + Ec;              // Ec
  int* offs    = cursor + Ec;              // Ec
  float* h1 = (float*)d_out;  // 4096*4096 fp32 scratch inside d_out (262MB); overwritten by LM head at the end

  k_embed<<<Sc, 256, 0, stream>>>(idx, tok, pos, x);
  for (int l = 0; l < Lc; l++) {
    k_ln<<<Sc, 256, 0, stream>>>(x, ln1g + l * Hc, ln1b + l * Hc, lnb);
    k_gemm_nt<<<dim3(Sc / TM, 3 * Hc / TN), 256, 0, stream>>>(
        lnb, wqkv + (size_t)l * 3 * Hc * Hc, bqkv + l * 3 * Hc, nullptr, qkv,
        Sc, 3 * Hc, Hc);
    k_attn_tile<<<dim3(Sc / 64, NHc), 256, 0, stream>>>(qkv, ctx);
    k_gemm_nt<<<dim3(Sc / TM, Hc / TN), 256, 0, stream>>>(
        ctx, wo + (size_t)l * Hc * Hc, bo + l * Hc, x, x, Sc, Hc, Hc);
    k_ln<<<Sc, 256, 0, stream>>>(x, ln2g + l * Hc, ln2b + l * Hc, lnb);
    hipMemsetAsync(counts, 0, 2 * Ec * sizeof(int), stream);
    k_router<<<Sc, 256, 0, stream>>>(lnb, rw + (size_t)l * Ec * Hc, topi, topw, counts);
    k_offs<<<1, 1, 0, stream>>>(counts, offs);
    k_scatter<<<Sc / 256, 256, 0, stream>>>(topi, topw, offs, cursor, elist, ecoef);
    k_moe_gemm1<<<dim3(Sc * Kc / TM, FFc / TN, Ec), 256, 0, stream>>>(
        lnb, w1 + (size_t)l * Ec * Hc * FFc, elist, counts, offs, h1);
    k_moe_gemm2<<<dim3(Sc * Kc / TM, Hc / TN, Ec), 256, 0, stream>>>(
        h1, w2 + (size_t)l * Ec * FFc * Hc, elist, ecoef, counts, offs, x);
  }
  k_ln<<<Sc, 256, 0, stream>>>(x, lnfg, lnfb, lnb);
  k_gemm_nt<<<dim3(Sc / TM, Vc / TN), 256, 0, stream>>>(
      lnb, tok, nullptr, nullptr, (float*)d_out, Sc, Vc, Hc);
}

// Round 9
// 8444.765 us; speedup vs baseline: 1.6669x; 1.1202x over previous
//
#include <hip/hip_runtime.h>
#include <hip/hip_bf16.h>

// Model config
#define Lc 2
#define Hc 1024
#define NHc 16
#define HDc 64
#define FFc 4096
#define Ec 8
#define Kc 2
#define Vc 32000
#define Sc 2048
#define EPSc 1e-5f

typedef short s16x8 __attribute__((ext_vector_type(8)));
typedef float f32x4 __attribute__((ext_vector_type(4)));
typedef unsigned short us4 __attribute__((ext_vector_type(4)));
typedef unsigned short us8 __attribute__((ext_vector_type(8)));

__device__ __forceinline__ unsigned short f2bf_r(float f) {
  unsigned u = __float_as_uint(f);
  u += 0x7FFFu + ((u >> 16) & 1u);
  return (unsigned short)(u >> 16);
}
__device__ __forceinline__ float bf2f(unsigned short h) {
  return __uint_as_float((unsigned)h << 16);
}
__device__ __forceinline__ void split2(float f, unsigned short& hi, unsigned short& lo) {
  hi = f2bf_r(f);
  lo = f2bf_r(f - bf2f(hi));
}

// ---------------- embedding ----------------
__global__ __launch_bounds__(256) void k_embed(const int* __restrict__ idx,
    const float* __restrict__ tok, const float* __restrict__ pos,
    float* __restrict__ x) {
  int t = blockIdx.x;
  int id = idx[t];
  for (int i = threadIdx.x; i < Hc; i += 256)
    x[t * Hc + i] = tok[(size_t)id * Hc + i] + pos[t * Hc + i];
}

// ---------------- layernorm: fp32 out + bf16 hi/lo planes ----------------
__global__ __launch_bounds__(256) void k_ln(const float* __restrict__ x,
    const float* __restrict__ g, const float* __restrict__ b,
    float* __restrict__ o, unsigned short* __restrict__ oh,
    unsigned short* __restrict__ ol) {
  int row = blockIdx.x;
  int tid = threadIdx.x;
  const float* xr = x + (size_t)row * Hc;
  float v[4];
  float s = 0.f;
#pragma unroll
  for (int i = 0; i < 4; i++) { v[i] = xr[tid + 256 * i]; s += v[i]; }
  __shared__ float red[256];
  red[tid] = s; __syncthreads();
  for (int st = 128; st > 0; st >>= 1) {
    if (tid < st) red[tid] += red[tid + st];
    __syncthreads();
  }
  float mu = red[0] * (1.0f / Hc);
  __syncthreads();
  float s2 = 0.f;
#pragma unroll
  for (int i = 0; i < 4; i++) { float d = v[i] - mu; s2 += d * d; }
  red[tid] = s2; __syncthreads();
  for (int st = 128; st > 0; st >>= 1) {
    if (tid < st) red[tid] += red[tid + st];
    __syncthreads();
  }
  float rs = rsqrtf(red[0] * (1.0f / Hc) + EPSc);
  float* orow = o + (size_t)row * Hc;
#pragma unroll
  for (int i = 0; i < 4; i++) {
    int c = tid + 256 * i;
    float ov = (v[i] - mu) * rs * g[c] + b[c];
    orow[c] = ov;
    unsigned short hh, ll;
    split2(ov, hh, ll);
    oh[(size_t)row * Hc + c] = hh;
    ol[(size_t)row * Hc + c] = ll;
  }
}

// ---------------- MFMA GEMM (3-product hi/lo): C = A[M,K] @ B^T ----------------
// A from bf16 hi/lo planes; B fp32, split to hi/lo during staging.
// acc = ah*bh + al*bh + ah*bl  (al*bl ~2^-18, dropped)
// MODE 0: dense A, C = acc (+bias)(+resid), fp32 out
// MODE 1: gather A rows via elist (expert z), gelu -> Oh/Ol bf16 planes
// MODE 2: dense A rows (off+r), atomicAdd coef*acc into C[tok]
// BT 0: B stored [N][K] (NT). BT 1: B stored [K][N] (TN, transpose-stage).
#define BMg 128
#define BNg 64
#define BKg 64

template <int MODE, int BT>
__global__ __launch_bounds__(256) void k_mfma_gemm(
    const unsigned short* __restrict__ Ah, const unsigned short* __restrict__ Al,
    const float* __restrict__ Bmat,
    const float* __restrict__ bias, const float* __restrict__ resid,
    float* __restrict__ C,
    unsigned short* __restrict__ Oh, unsigned short* __restrict__ Ol,
    const int* __restrict__ elist, const float* __restrict__ ecoef,
    const int* __restrict__ counts, const int* __restrict__ offs,
    int M, int N, int K) {
  int cnt = 0, off = 0;
  if (MODE >= 1) {
    int e = blockIdx.z;
    cnt = counts[e]; off = offs[e];
    if ((int)(blockIdx.x * BMg) >= cnt) return;
    Bmat += (size_t)e * (size_t)K * N;
  }
  int m0 = blockIdx.x * BMg, n0 = blockIdx.y * BNg;
  int tid = threadIdx.x;
  int l = tid & 63, w = tid >> 6;
  int wm = (w >> 1) * 64, wn = (w & 1) * 32;
  int lr = l & 15, kg = l >> 4;

  __shared__ unsigned short Ahs[BMg][72];
  __shared__ unsigned short Als[BMg][72];
  __shared__ unsigned short Bhs[BNg][72];
  __shared__ unsigned short Bls[BNg][72];

  f32x4 acc[4][2] = {};

  int sr = tid >> 1;            // 0..127 (A row)
  int sc = (tid & 1) * 32;      // A k offset
  int sr2 = tid >> 2;           // 0..63 (B n-row NT / k-row TN)
  int sc2 = (tid & 3) * 16;     // B k offset (NT) / n offset (TN)

  int arow;
  if (MODE == 0) arow = m0 + sr;
  else if (MODE == 1) arow = (m0 + sr < cnt) ? elist[off + m0 + sr] : -1;
  else arow = (m0 + sr < cnt) ? (off + m0 + sr) : -1;

  for (int k0 = 0; k0 < K; k0 += BKg) {
    // ---- stage A hi/lo ----
    if (arow >= 0) {
      const unsigned short* ph = Ah + (size_t)arow * K + k0 + sc;
      const unsigned short* pl = Al + (size_t)arow * K + k0 + sc;
#pragma unroll
      for (int c = 0; c < 4; ++c) {
        *(us8*)&Ahs[sr][sc + 8 * c] = *(const us8*)(ph + 8 * c);
        *(us8*)&Als[sr][sc + 8 * c] = *(const us8*)(pl + 8 * c);
      }
    } else {
      us8 z = {0, 0, 0, 0, 0, 0, 0, 0};
#pragma unroll
      for (int c = 0; c < 4; ++c) {
        *(us8*)&Ahs[sr][sc + 8 * c] = z;
        *(us8*)&Als[sr][sc + 8 * c] = z;
      }
    }
    // ---- stage B hi/lo (fp32 -> exact bf16 split) ----
    if (BT == 0) {
      const float* pb = Bmat + (size_t)(n0 + sr2) * K + k0 + sc2;
#pragma unroll
      for (int c = 0; c < 4; ++c) {
        float4 v = *(const float4*)(pb + 4 * c);
        us4 h4, l4;
        unsigned short th, tl;
        split2(v.x, th, tl); h4.x = th; l4.x = tl;
        split2(v.y, th, tl); h4.y = th; l4.y = tl;
        split2(v.z, th, tl); h4.z = th; l4.z = tl;
        split2(v.w, th, tl); h4.w = th; l4.w = tl;
        *(us4*)&Bhs[sr2][sc2 + 4 * c] = h4;
        *(us4*)&Bls[sr2][sc2 + 4 * c] = l4;
      }
    } else {
      const float* pb = Bmat + (size_t)(k0 + sr2) * N + n0 + sc2;
#pragma unroll
      for (int c = 0; c < 4; ++c) {
        float4 v = *(const float4*)(pb + 4 * c);
        unsigned short hh, ll;
        split2(v.x, hh, ll); Bhs[sc2 + 4 * c + 0][sr2] = hh; Bls[sc2 + 4 * c + 0][sr2] = ll;
        split2(v.y, hh, ll); Bhs[sc2 + 4 * c + 1][sr2] = hh; Bls[sc2 + 4 * c + 1][sr2] = ll;
        split2(v.z, hh, ll); Bhs[sc2 + 4 * c + 2][sr2] = hh; Bls[sc2 + 4 * c + 2][sr2] = ll;
        split2(v.w, hh, ll); Bhs[sc2 + 4 * c + 3][sr2] = hh; Bls[sc2 + 4 * c + 3][sr2] = ll;
      }
    }
    __syncthreads();
    // ---- compute ----
#pragma unroll
    for (int ks = 0; ks < 2; ++ks) {
      int kk = ks * 32 + kg * 8;
      s16x8 bh[2], bl[2];
#pragma unroll
      for (int nf = 0; nf < 2; ++nf) {
        bh[nf] = *(const s16x8*)&Bhs[wn + nf * 16 + lr][kk];
        bl[nf] = *(const s16x8*)&Bls[wn + nf * 16 + lr][kk];
      }
#pragma unroll
      for (int mf = 0; mf < 4; ++mf) {
        s16x8 ah = *(const s16x8*)&Ahs[wm + mf * 16 + lr][kk];
        s16x8 al = *(const s16x8*)&Als[wm + mf * 16 + lr][kk];
#pragma unroll
        for (int nf = 0; nf < 2; ++nf) {
          acc[mf][nf] = __builtin_amdgcn_mfma_f32_16x16x32_bf16(ah, bh[nf], acc[mf][nf], 0, 0, 0);
          acc[mf][nf] = __builtin_amdgcn_mfma_f32_16x16x32_bf16(al, bh[nf], acc[mf][nf], 0, 0, 0);
          acc[mf][nf] = __builtin_amdgcn_mfma_f32_16x16x32_bf16(ah, bl[nf], acc[mf][nf], 0, 0, 0);
        }
      }
    }
    __syncthreads();
  }

  // ---- epilogue ----
  int rbase = (l >> 4) * 4;
#pragma unroll
  for (int mf = 0; mf < 4; ++mf) {
#pragma unroll
    for (int nf = 0; nf < 2; ++nf) {
      int n = n0 + wn + nf * 16 + lr;
#pragma unroll
      for (int j = 0; j < 4; ++j) {
        int rloc = m0 + wm + mf * 16 + rbase + j;
        float v = acc[mf][nf][j];
        if (MODE == 0) {
          if (bias) v += bias[n];
          if (resid) v += resid[(size_t)rloc * N + n];
          C[(size_t)rloc * N + n] = v;
        } else if (MODE == 1) {
          if (rloc < cnt) {
            float g = 0.5f * v * (1.0f + erff(v * 0.70710678118654752f));
            unsigned short hh, ll;
            split2(g, hh, ll);
            size_t p = (size_t)(off + rloc) * N + n;
            Oh[p] = hh; Ol[p] = ll;
          }
        } else {
          if (rloc < cnt) {
            int tok = elist[off + rloc];
            float cf = ecoef[off + rloc];
            atomicAdd(&C[(size_t)tok * N + n], cf * v);
          }
        }
      }
    }
  }
}

// ---------------- tiled flash attention (epilogue -> bf16 hi/lo ctx planes) ----------------
__global__ __launch_bounds__(256) void k_attn_tile(const float* __restrict__ qkv,
                                                   unsigned short* __restrict__ ctx_hi,
                                                   unsigned short* __restrict__ ctx_lo) {
  int qt = blockIdx.x, h = blockIdx.y;
  int q0 = qt * 64;
  int tid = threadIdx.x;
  int tx = tid & 15, ty = tid >> 4;

  __shared__ float Qs[64][68];   // Q^T: [d][q]
  __shared__ float KPs[64][68];  // K^T: [d][j], reused as P^T: [j][q]
  __shared__ float Vs[64][68];   // V:   [j][d]

  float oacc[4][4] = {};
  float m[4] = {-INFINITY, -INFINITY, -INFINITY, -INFINITY};
  float l[4] = {0.f, 0.f, 0.f, 0.f};

  int lrr = tid >> 2;
  int d0 = (tid & 3) * 16;

  {
    const float* qbase = qkv + (size_t)(q0 + lrr) * 3072 + h * 64 + d0;
#pragma unroll
    for (int c = 0; c < 4; ++c) {
      float4 qv = *(const float4*)(qbase + 4 * c);
      Qs[d0 + 4 * c + 0][lrr] = qv.x * 0.125f;
      Qs[d0 + 4 * c + 1][lrr] = qv.y * 0.125f;
      Qs[d0 + 4 * c + 2][lrr] = qv.z * 0.125f;
      Qs[d0 + 4 * c + 3][lrr] = qv.w * 0.125f;
    }
  }
  __syncthreads();

  for (int jt = 0; jt <= qt; ++jt) {
    int j0 = jt * 64;
    {
      const float* kbase = qkv + (size_t)(j0 + lrr) * 3072 + 1024 + h * 64 + d0;
      const float* vbase = qkv + (size_t)(j0 + lrr) * 3072 + 2048 + h * 64 + d0;
#pragma unroll
      for (int c = 0; c < 4; ++c) {
        float4 kv = *(const float4*)(kbase + 4 * c);
        KPs[d0 + 4 * c + 0][lrr] = kv.x;
        KPs[d0 + 4 * c + 1][lrr] = kv.y;
        KPs[d0 + 4 * c + 2][lrr] = kv.z;
        KPs[d0 + 4 * c + 3][lrr] = kv.w;
        *(float4*)&Vs[lrr][d0 + 4 * c] = *(const float4*)(vbase + 4 * c);
      }
    }
    __syncthreads();

    float sacc[4][4] = {};
#pragma unroll 8
    for (int kk = 0; kk < 64; ++kk) {
      float4 a = *(const float4*)&Qs[kk][ty * 4];
      float4 b = *(const float4*)&KPs[kk][tx * 4];
      const float* ap = (const float*)&a;
      const float* bp = (const float*)&b;
#pragma unroll
      for (int i = 0; i < 4; ++i)
#pragma unroll
        for (int jj = 0; jj < 4; ++jj)
          sacc[i][jj] = fmaf(ap[i], bp[jj], sacc[i][jj]);
    }

    if (jt == qt) {
#pragma unroll
      for (int i = 0; i < 4; ++i)
#pragma unroll
        for (int jj = 0; jj < 4; ++jj)
          if (tx * 4 + jj > ty * 4 + i) sacc[i][jj] = -INFINITY;
    }

#pragma unroll
    for (int i = 0; i < 4; ++i) {
      float rm = fmaxf(fmaxf(sacc[i][0], sacc[i][1]),
                       fmaxf(sacc[i][2], sacc[i][3]));
#pragma unroll
      for (int o = 8; o > 0; o >>= 1) rm = fmaxf(rm, __shfl_xor(rm, o, 64));
      float mnew = fmaxf(m[i], rm);
      float alpha = __expf(m[i] - mnew);
      float rs = 0.f;
#pragma unroll
      for (int jj = 0; jj < 4; ++jj) {
        float p = __expf(sacc[i][jj] - mnew);
        sacc[i][jj] = p;
        rs += p;
      }
#pragma unroll
      for (int o = 8; o > 0; o >>= 1) rs += __shfl_xor(rs, o, 64);
      l[i] = l[i] * alpha + rs;
      m[i] = mnew;
#pragma unroll
      for (int jj = 0; jj < 4; ++jj) oacc[i][jj] *= alpha;
    }

    __syncthreads();
#pragma unroll
    for (int i = 0; i < 4; ++i)
#pragma unroll
      for (int jj = 0; jj < 4; ++jj)
        KPs[tx * 4 + jj][ty * 4 + i] = sacc[i][jj];
    __syncthreads();

#pragma unroll 8
    for (int kk = 0; kk < 64; ++kk) {
      float4 a = *(const float4*)&KPs[kk][ty * 4];
      float4 b = *(const float4*)&Vs[kk][tx * 4];
      const float* ap = (const float*)&a;
      const float* bp = (const float*)&b;
#pragma unroll
      for (int i = 0; i < 4; ++i)
#pragma unroll
        for (int jj = 0; jj < 4; ++jj)
          oacc[i][jj] = fmaf(ap[i], bp[jj], oacc[i][jj]);
    }
    __syncthreads();
  }

#pragma unroll
  for (int i = 0; i < 4; ++i) {
    float inv = 1.0f / l[i];
    int mrow = q0 + ty * 4 + i;
    size_t base = (size_t)mrow * Hc + h * 64 + tx * 4;
    us4 hv, lv;
#pragma unroll
    for (int jj = 0; jj < 4; ++jj) {
      float v = oacc[i][jj] * inv;
      unsigned short hh, ll;
      split2(v, hh, ll);
      hv[jj] = hh; lv[jj] = ll;
    }
    *(us4*)&ctx_hi[base] = hv;
    *(us4*)&ctx_lo[base] = lv;
  }
}

// ---------------- router: softmax over 8 experts + top-2 + counts ----------------
__global__ __launch_bounds__(256) void k_router(const float* __restrict__ xf,
    const float* __restrict__ rw, int* __restrict__ topi,
    float* __restrict__ topw, int* __restrict__ counts) {
  int t = blockIdx.x;
  int tid = threadIdx.x;
  int e = tid >> 5, l = tid & 31;
  const float* xr = xf + (size_t)t * Hc;
  const float* we = rw + (size_t)e * Hc;
  float s = 0.f;
  for (int hh = l; hh < Hc; hh += 32) s += xr[hh] * we[hh];
  __shared__ float red[256];
  red[tid] = s; __syncthreads();
  for (int st = 16; st > 0; st >>= 1) {
    if (l < st) red[tid] += red[tid + st];
    __syncthreads();
  }
  if (tid == 0) {
    float lg[Ec], pr[Ec];
    float mx = -INFINITY;
    for (int k = 0; k < Ec; k++) { lg[k] = red[k * 32]; mx = fmaxf(mx, lg[k]); }
    float ps = 0.f;
    for (int k = 0; k < Ec; k++) { pr[k] = expf(lg[k] - mx); ps += pr[k]; }
    float inv = 1.0f / ps;
    for (int k = 0; k < Ec; k++) pr[k] *= inv;
    int i1 = 0;
    for (int k = 1; k < Ec; k++) if (pr[k] > pr[i1]) i1 = k;
    int i2 = (i1 == 0) ? 1 : 0;
    for (int k = 0; k < Ec; k++)
      if (k != i1 && pr[k] > pr[i2]) i2 = k;
    topi[2 * t] = i1; topi[2 * t + 1] = i2;
    topw[2 * t] = pr[i1]; topw[2 * t + 1] = pr[i2];
    atomicAdd(&counts[i1], 1);
    atomicAdd(&counts[i2], 1);
  }
}

__global__ void k_offs(const int* __restrict__ counts, int* __restrict__ offs) {
  int acc = 0;
  for (int e = 0; e < Ec; e++) { offs[e] = acc; acc += counts[e]; }
}

__global__ __launch_bounds__(256) void k_scatter(const int* __restrict__ topi,
    const float* __restrict__ topw, const int* __restrict__ offs,
    int* __restrict__ cursor, int* __restrict__ elist,
    float* __restrict__ ecoef) {
  int t = blockIdx.x * 256 + threadIdx.x;
  if (t >= Sc) return;
#pragma unroll
  for (int s = 0; s < Kc; s++) {
    int e = topi[2 * t + s];
    int p = atomicAdd(&cursor[e], 1);
    int gslot = offs[e] + p;
    elist[gslot] = t;
    ecoef[gslot] = topw[2 * t + s];
  }
}

extern "C" void kernel_launch(void* const* d_in, const int* in_sizes, int n_in,
                              void* d_out, int out_size, void* d_ws, size_t ws_size,
                              hipStream_t stream) {
  const int*   idx   = (const int*)d_in[0];
  const float* tok   = (const float*)d_in[1];
  const float* pos   = (const float*)d_in[2];
  const float* ln1g  = (const float*)d_in[3];
  const float* ln1b  = (const float*)d_in[4];
  const float* wqkv  = (const float*)d_in[5];
  const float* bqkv  = (const float*)d_in[6];
  const float* wo    = (const float*)d_in[7];
  const float* bo    = (const float*)d_in[8];
  const float* ln2g  = (const float*)d_in[9];
  const float* ln2b  = (const float*)d_in[10];
  const float* rw    = (const float*)d_in[11];
  const float* w1    = (const float*)d_in[12];
  const float* w2    = (const float*)d_in[13];
  const float* lnfg  = (const float*)d_in[14];
  const float* lnfb  = (const float*)d_in[15];

  float* ws   = (float*)d_ws;
  float* x    = ws;                    // Sc*Hc
  float* lnb  = x + Sc * Hc;           // Sc*Hc
  float* qkv  = lnb + Sc * Hc;         // Sc*3*Hc
  float* topw  = qkv + Sc * 3 * Hc;    // Sc*Kc
  float* ecoef = topw + Sc * Kc;       // Sc*Kc
  int* topi    = (int*)(ecoef + Sc * Kc);  // Sc*Kc
  int* elist   = topi + Sc * Kc;           // Sc*Kc
  int* counts  = elist + Sc * Kc;          // Ec
  int* cursor  = counts + Ec;              // Ec
  int* offs    = cursor + Ec;              // Ec
  unsigned short* lnb_hi = (unsigned short*)(offs + Ec);   // Sc*Hc ushort
  unsigned short* lnb_lo = lnb_hi + (size_t)Sc * Hc;       // Sc*Hc ushort

  // d_out scratch (262 MB): h1 bf16 planes + ctx bf16 planes; all consumed
  // before the LM head overwrites d_out with logits.
  unsigned short* h1_hi  = (unsigned short*)d_out;                 // Sc*Kc*FFc
  unsigned short* h1_lo  = h1_hi + (size_t)Sc * Kc * FFc;
  unsigned short* ctx_hi = h1_lo + (size_t)Sc * Kc * FFc;          // Sc*Hc
  unsigned short* ctx_lo = ctx_hi + (size_t)Sc * Hc;

  k_embed<<<Sc, 256, 0, stream>>>(idx, tok, pos, x);
  for (int l = 0; l < Lc; l++) {
    k_ln<<<Sc, 256, 0, stream>>>(x, ln1g + l * Hc, ln1b + l * Hc, lnb, lnb_hi, lnb_lo);
    // QKV: [S,3H] = lnb @ wqkv^T + bqkv
    k_mfma_gemm<0, 0><<<dim3(Sc / BMg, 3 * Hc / BNg), 256, 0, stream>>>(
        lnb_hi, lnb_lo, wqkv + (size_t)l * 3 * Hc * Hc, bqkv + l * 3 * Hc,
        nullptr, qkv, nullptr, nullptr, nullptr, nullptr, nullptr, nullptr,
        Sc, 3 * Hc, Hc);
    k_attn_tile<<<dim3(Sc / 64, NHc), 256, 0, stream>>>(qkv, ctx_hi, ctx_lo);
    // WO: x += ctx @ wo^T + bo
    k_mfma_gemm<0, 0><<<dim3(Sc / BMg, Hc / BNg), 256, 0, stream>>>(
        ctx_hi, ctx_lo, wo + (size_t)l * Hc * Hc, bo + l * Hc, x, x,
        nullptr, nullptr, nullptr, nullptr, nullptr, nullptr, Sc, Hc, Hc);
    k_ln<<<Sc, 256, 0, stream>>>(x, ln2g + l * Hc, ln2b + l * Hc, lnb, lnb_hi, lnb_lo);
    hipMemsetAsync(counts, 0, 2 * Ec * sizeof(int), stream);
    k_router<<<Sc, 256, 0, stream>>>(lnb, rw + (size_t)l * Ec * Hc, topi, topw, counts);
    k_offs<<<1, 1, 0, stream>>>(counts, offs);
    k_scatter<<<Sc / 256, 256, 0, stream>>>(topi, topw, offs, cursor, elist, ecoef);
    // MoE GEMM1: h1 = gelu(gather(lnb) @ w1[e]); w1 is [K=H][N=FF]
    k_mfma_gemm<1, 1><<<dim3(Sc * Kc / BMg, FFc / BNg, Ec), 256, 0, stream>>>(
        lnb_hi, lnb_lo, w1 + (size_t)l * Ec * Hc * FFc, nullptr, nullptr,
        nullptr, h1_hi, h1_lo, elist, nullptr, counts, offs, Sc * Kc, FFc, Hc);
    // MoE GEMM2: x[tok] += coef * (h1 @ w2[e]); w2 is [K=FF][N=H]
    k_mfma_gemm<2, 1><<<dim3(Sc * Kc / BMg, Hc / BNg, Ec), 256, 0, stream>>>(
        h1_hi, h1_lo, w2 + (size_t)l * Ec * FFc * Hc, nullptr, nullptr,
        x, nullptr, nullptr, elist, ecoef, counts, offs, Sc * Kc, Hc, FFc);
  }
  k_ln<<<Sc, 256, 0, stream>>>(x, lnfg, lnfb, lnb, lnb_hi, lnb_lo);
  // LM head: logits = lnb @ tok^T
  k_mfma_gemm<0, 0><<<dim3(Sc / BMg, Vc / BNg), 256, 0, stream>>>(
      lnb_hi, lnb_lo, tok, nullptr, nullptr, (float*)d_out,
      nullptr, nullptr, nullptr, nullptr, nullptr, nullptr, Sc, Vc, Hc);
}

// Round 10
// 7842.500 us; speedup vs baseline: 1.7949x; 1.0768x over previous
//
#include <hip/hip_runtime.h>
#include <hip/hip_bf16.h>

// Model config
#define Lc 2
#define Hc 1024
#define NHc 16
#define HDc 64
#define FFc 4096
#define Ec 8
#define Kc 2
#define Vc 32000
#define Sc 2048
#define EPSc 1e-5f

typedef short s16x8 __attribute__((ext_vector_type(8)));
typedef float f32x4 __attribute__((ext_vector_type(4)));
typedef unsigned short us4 __attribute__((ext_vector_type(4)));
typedef unsigned short us8 __attribute__((ext_vector_type(8)));

__device__ __forceinline__ unsigned short f2bf_r(float f) {
  unsigned u = __float_as_uint(f);
  u += 0x7FFFu + ((u >> 16) & 1u);
  return (unsigned short)(u >> 16);
}
__device__ __forceinline__ float bf2f(unsigned short h) {
  return __uint_as_float((unsigned)h << 16);
}
__device__ __forceinline__ void split2(float f, unsigned short& hi, unsigned short& lo) {
  hi = f2bf_r(f);
  lo = f2bf_r(f - bf2f(hi));
}

// ---------------- embedding ----------------
__global__ __launch_bounds__(256) void k_embed(const int* __restrict__ idx,
    const float* __restrict__ tok, const float* __restrict__ pos,
    float* __restrict__ x) {
  int t = blockIdx.x;
  int id = idx[t];
  for (int i = threadIdx.x; i < Hc; i += 256)
    x[t * Hc + i] = tok[(size_t)id * Hc + i] + pos[t * Hc + i];
}

// ---------------- layernorm: fp32 out + bf16 hi/lo planes ----------------
__global__ __launch_bounds__(256) void k_ln(const float* __restrict__ x,
    const float* __restrict__ g, const float* __restrict__ b,
    float* __restrict__ o, unsigned short* __restrict__ oh,
    unsigned short* __restrict__ ol) {
  int row = blockIdx.x;
  int tid = threadIdx.x;
  const float* xr = x + (size_t)row * Hc;
  float v[4];
  float s = 0.f;
#pragma unroll
  for (int i = 0; i < 4; i++) { v[i] = xr[tid + 256 * i]; s += v[i]; }
  __shared__ float red[256];
  red[tid] = s; __syncthreads();
  for (int st = 128; st > 0; st >>= 1) {
    if (tid < st) red[tid] += red[tid + st];
    __syncthreads();
  }
  float mu = red[0] * (1.0f / Hc);
  __syncthreads();
  float s2 = 0.f;
#pragma unroll
  for (int i = 0; i < 4; i++) { float d = v[i] - mu; s2 += d * d; }
  red[tid] = s2; __syncthreads();
  for (int st = 128; st > 0; st >>= 1) {
    if (tid < st) red[tid] += red[tid + st];
    __syncthreads();
  }
  float rs = rsqrtf(red[0] * (1.0f / Hc) + EPSc);
  float* orow = o + (size_t)row * Hc;
#pragma unroll
  for (int i = 0; i < 4; i++) {
    int c = tid + 256 * i;
    float ov = (v[i] - mu) * rs * g[c] + b[c];
    orow[c] = ov;
    unsigned short hh, ll;
    split2(ov, hh, ll);
    oh[(size_t)row * Hc + c] = hh;
    ol[(size_t)row * Hc + c] = ll;
  }
}

// ---------------- MFMA GEMM (3-product hi/lo, reg-staged pipeline) ----------------
// C = A[M,K] @ B^T; A from bf16 hi/lo planes; B fp32, split during staging.
// acc = ah*bh + al*bh + ah*bl  (al*bl ~2^-18, dropped)
// MODE 0: dense A, C = acc (+bias)(+resid), fp32 out
// MODE 1: gather A rows via elist (expert z), gelu -> Oh/Ol bf16 planes
// MODE 2: dense A rows (off+r), atomicAdd coef*acc into C[tok]
// BT 0: B stored [N][K] (NT). BT 1: B stored [K][N] (TN, transpose-stage).
// __launch_bounds__(256,2): LDS caps at 2 blocks/CU anyway; allow 256 VGPRs so
// all staging loads stay in flight (round-9 counters: VGPR=88 serialized them).
#define BMg 128
#define BNg 64
#define BKg 64

template <int MODE, int BT>
__global__ __launch_bounds__(256, 2) void k_mfma_gemm(
    const unsigned short* __restrict__ Ah, const unsigned short* __restrict__ Al,
    const float* __restrict__ Bmat,
    const float* __restrict__ bias, const float* __restrict__ resid,
    float* __restrict__ C,
    unsigned short* __restrict__ Oh, unsigned short* __restrict__ Ol,
    const int* __restrict__ elist, const float* __restrict__ ecoef,
    const int* __restrict__ counts, const int* __restrict__ offs,
    int M, int N, int K) {
  int cnt = 0, off = 0;
  if (MODE >= 1) {
    int e = blockIdx.z;
    cnt = counts[e]; off = offs[e];
    if ((int)(blockIdx.x * BMg) >= cnt) return;
    Bmat += (size_t)e * (size_t)K * N;
  }
  int m0 = blockIdx.x * BMg, n0 = blockIdx.y * BNg;
  int tid = threadIdx.x;
  int l = tid & 63, w = tid >> 6;
  int wm = (w >> 1) * 64, wn = (w & 1) * 32;
  int lr = l & 15, kg = l >> 4;

  __shared__ unsigned short Ahs[BMg][72];
  __shared__ unsigned short Als[BMg][72];
  __shared__ unsigned short Bhs[BNg][72];
  __shared__ unsigned short Bls[BNg][72];

  f32x4 acc[4][2] = {};

  int sr = tid >> 1;            // 0..127 (A row)
  int sc = (tid & 1) * 32;      // A k offset
  int sr2 = tid >> 2;           // 0..63 (B n-row NT / k-row TN)
  int sc2 = (tid & 3) * 16;     // B k offset (NT) / n offset (TN)

  int arow;
  if (MODE == 0) arow = m0 + sr;
  else if (MODE == 1) arow = (m0 + sr < cnt) ? elist[off + m0 + sr] : -1;
  else arow = (m0 + sr < cnt) ? (off + m0 + sr) : -1;

  // register staging buffers (tile in flight)
  us8 ra[4], rl4[4];
  float4 rb[4];

  auto load_tile = [&](int k0) {
    if (arow >= 0) {
      const unsigned short* ph = Ah + (size_t)arow * K + k0 + sc;
      const unsigned short* pl = Al + (size_t)arow * K + k0 + sc;
#pragma unroll
      for (int c = 0; c < 4; ++c) {
        ra[c]  = *(const us8*)(ph + 8 * c);
        rl4[c] = *(const us8*)(pl + 8 * c);
      }
    } else {
      us8 z = {0, 0, 0, 0, 0, 0, 0, 0};
#pragma unroll
      for (int c = 0; c < 4; ++c) { ra[c] = z; rl4[c] = z; }
    }
    const float* pb = (BT == 0)
        ? Bmat + (size_t)(n0 + sr2) * K + k0 + sc2
        : Bmat + (size_t)(k0 + sr2) * N + n0 + sc2;
#pragma unroll
    for (int c = 0; c < 4; ++c) rb[c] = *(const float4*)(pb + 4 * c);
  };

  auto store_tile = [&]() {
#pragma unroll
    for (int c = 0; c < 4; ++c) {
      *(us8*)&Ahs[sr][sc + 8 * c] = ra[c];
      *(us8*)&Als[sr][sc + 8 * c] = rl4[c];
    }
    if (BT == 0) {
#pragma unroll
      for (int c = 0; c < 4; ++c) {
        float4 v = rb[c];
        us4 h4, l4;
        unsigned short th, tl;
        split2(v.x, th, tl); h4.x = th; l4.x = tl;
        split2(v.y, th, tl); h4.y = th; l4.y = tl;
        split2(v.z, th, tl); h4.z = th; l4.z = tl;
        split2(v.w, th, tl); h4.w = th; l4.w = tl;
        *(us4*)&Bhs[sr2][sc2 + 4 * c] = h4;
        *(us4*)&Bls[sr2][sc2 + 4 * c] = l4;
      }
    } else {
#pragma unroll
      for (int c = 0; c < 4; ++c) {
        float4 v = rb[c];
        unsigned short hh, ll;
        split2(v.x, hh, ll); Bhs[sc2 + 4 * c + 0][sr2] = hh; Bls[sc2 + 4 * c + 0][sr2] = ll;
        split2(v.y, hh, ll); Bhs[sc2 + 4 * c + 1][sr2] = hh; Bls[sc2 + 4 * c + 1][sr2] = ll;
        split2(v.z, hh, ll); Bhs[sc2 + 4 * c + 2][sr2] = hh; Bls[sc2 + 4 * c + 2][sr2] = ll;
        split2(v.w, hh, ll); Bhs[sc2 + 4 * c + 3][sr2] = hh; Bls[sc2 + 4 * c + 3][sr2] = ll;
      }
    }
  };

  load_tile(0);
  for (int k0 = 0; k0 < K; k0 += BKg) {
    store_tile();        // consumes regs of tile k0 (waitcnt had full compute phase of slack)
    __syncthreads();     // LDS tile visible
    if (k0 + BKg < K) load_tile(k0 + BKg);  // issue next tile's loads; hide under compute
    // ---- compute on LDS tile ----
#pragma unroll
    for (int ks = 0; ks < 2; ++ks) {
      int kk = ks * 32 + kg * 8;
      s16x8 bh[2], bl[2];
#pragma unroll
      for (int nf = 0; nf < 2; ++nf) {
        bh[nf] = *(const s16x8*)&Bhs[wn + nf * 16 + lr][kk];
        bl[nf] = *(const s16x8*)&Bls[wn + nf * 16 + lr][kk];
      }
#pragma unroll
      for (int mf = 0; mf < 4; ++mf) {
        s16x8 ah = *(const s16x8*)&Ahs[wm + mf * 16 + lr][kk];
        s16x8 al = *(const s16x8*)&Als[wm + mf * 16 + lr][kk];
#pragma unroll
        for (int nf = 0; nf < 2; ++nf) {
          acc[mf][nf] = __builtin_amdgcn_mfma_f32_16x16x32_bf16(ah, bh[nf], acc[mf][nf], 0, 0, 0);
          acc[mf][nf] = __builtin_amdgcn_mfma_f32_16x16x32_bf16(al, bh[nf], acc[mf][nf], 0, 0, 0);
          acc[mf][nf] = __builtin_amdgcn_mfma_f32_16x16x32_bf16(ah, bl[nf], acc[mf][nf], 0, 0, 0);
        }
      }
    }
    __syncthreads();     // all reads done before next store_tile overwrites LDS
  }

  // ---- epilogue ----
  int rbase = (l >> 4) * 4;
#pragma unroll
  for (int mf = 0; mf < 4; ++mf) {
#pragma unroll
    for (int nf = 0; nf < 2; ++nf) {
      int n = n0 + wn + nf * 16 + lr;
#pragma unroll
      for (int j = 0; j < 4; ++j) {
        int rloc = m0 + wm + mf * 16 + rbase + j;
        float v = acc[mf][nf][j];
        if (MODE == 0) {
          if (bias) v += bias[n];
          if (resid) v += resid[(size_t)rloc * N + n];
          C[(size_t)rloc * N + n] = v;
        } else if (MODE == 1) {
          if (rloc < cnt) {
            float g = 0.5f * v * (1.0f + erff(v * 0.70710678118654752f));
            unsigned short hh, ll;
            split2(g, hh, ll);
            size_t p = (size_t)(off + rloc) * N + n;
            Oh[p] = hh; Ol[p] = ll;
          }
        } else {
          if (rloc < cnt) {
            int tok = elist[off + rloc];
            float cf = ecoef[off + rloc];
            atomicAdd(&C[(size_t)tok * N + n], cf * v);
          }
        }
      }
    }
  }
}

// ---------------- tiled flash attention (epilogue -> bf16 hi/lo ctx planes) ----------------
__global__ __launch_bounds__(256) void k_attn_tile(const float* __restrict__ qkv,
                                                   unsigned short* __restrict__ ctx_hi,
                                                   unsigned short* __restrict__ ctx_lo) {
  int qt = blockIdx.x, h = blockIdx.y;
  int q0 = qt * 64;
  int tid = threadIdx.x;
  int tx = tid & 15, ty = tid >> 4;

  __shared__ float Qs[64][68];   // Q^T: [d][q]
  __shared__ float KPs[64][68];  // K^T: [d][j], reused as P^T: [j][q]
  __shared__ float Vs[64][68];   // V:   [j][d]

  float oacc[4][4] = {};
  float m[4] = {-INFINITY, -INFINITY, -INFINITY, -INFINITY};
  float l[4] = {0.f, 0.f, 0.f, 0.f};

  int lrr = tid >> 2;
  int d0 = (tid & 3) * 16;

  {
    const float* qbase = qkv + (size_t)(q0 + lrr) * 3072 + h * 64 + d0;
#pragma unroll
    for (int c = 0; c < 4; ++c) {
      float4 qv = *(const float4*)(qbase + 4 * c);
      Qs[d0 + 4 * c + 0][lrr] = qv.x * 0.125f;
      Qs[d0 + 4 * c + 1][lrr] = qv.y * 0.125f;
      Qs[d0 + 4 * c + 2][lrr] = qv.z * 0.125f;
      Qs[d0 + 4 * c + 3][lrr] = qv.w * 0.125f;
    }
  }
  __syncthreads();

  for (int jt = 0; jt <= qt; ++jt) {
    int j0 = jt * 64;
    {
      const float* kbase = qkv + (size_t)(j0 + lrr) * 3072 + 1024 + h * 64 + d0;
      const float* vbase = qkv + (size_t)(j0 + lrr) * 3072 + 2048 + h * 64 + d0;
#pragma unroll
      for (int c = 0; c < 4; ++c) {
        float4 kv = *(const float4*)(kbase + 4 * c);
        KPs[d0 + 4 * c + 0][lrr] = kv.x;
        KPs[d0 + 4 * c + 1][lrr] = kv.y;
        KPs[d0 + 4 * c + 2][lrr] = kv.z;
        KPs[d0 + 4 * c + 3][lrr] = kv.w;
        *(float4*)&Vs[lrr][d0 + 4 * c] = *(const float4*)(vbase + 4 * c);
      }
    }
    __syncthreads();

    float sacc[4][4] = {};
#pragma unroll 8
    for (int kk = 0; kk < 64; ++kk) {
      float4 a = *(const float4*)&Qs[kk][ty * 4];
      float4 b = *(const float4*)&KPs[kk][tx * 4];
      const float* ap = (const float*)&a;
      const float* bp = (const float*)&b;
#pragma unroll
      for (int i = 0; i < 4; ++i)
#pragma unroll
        for (int jj = 0; jj < 4; ++jj)
          sacc[i][jj] = fmaf(ap[i], bp[jj], sacc[i][jj]);
    }

    if (jt == qt) {
#pragma unroll
      for (int i = 0; i < 4; ++i)
#pragma unroll
        for (int jj = 0; jj < 4; ++jj)
          if (tx * 4 + jj > ty * 4 + i) sacc[i][jj] = -INFINITY;
    }

#pragma unroll
    for (int i = 0; i < 4; ++i) {
      float rm = fmaxf(fmaxf(sacc[i][0], sacc[i][1]),
                       fmaxf(sacc[i][2], sacc[i][3]));
#pragma unroll
      for (int o = 8; o > 0; o >>= 1) rm = fmaxf(rm, __shfl_xor(rm, o, 64));
      float mnew = fmaxf(m[i], rm);
      float alpha = __expf(m[i] - mnew);
      float rs = 0.f;
#pragma unroll
      for (int jj = 0; jj < 4; ++jj) {
        float p = __expf(sacc[i][jj] - mnew);
        sacc[i][jj] = p;
        rs += p;
      }
#pragma unroll
      for (int o = 8; o > 0; o >>= 1) rs += __shfl_xor(rs, o, 64);
      l[i] = l[i] * alpha + rs;
      m[i] = mnew;
#pragma unroll
      for (int jj = 0; jj < 4; ++jj) oacc[i][jj] *= alpha;
    }

    __syncthreads();
#pragma unroll
    for (int i = 0; i < 4; ++i)
#pragma unroll
      for (int jj = 0; jj < 4; ++jj)
        KPs[tx * 4 + jj][ty * 4 + i] = sacc[i][jj];
    __syncthreads();

#pragma unroll 8
    for (int kk = 0; kk < 64; ++kk) {
      float4 a = *(const float4*)&KPs[kk][ty * 4];
      float4 b = *(const float4*)&Vs[kk][tx * 4];
      const float* ap = (const float*)&a;
      const float* bp = (const float*)&b;
#pragma unroll
      for (int i = 0; i < 4; ++i)
#pragma unroll
        for (int jj = 0; jj < 4; ++jj)
          oacc[i][jj] = fmaf(ap[i], bp[jj], oacc[i][jj]);
    }
    __syncthreads();
  }

#pragma unroll
  for (int i = 0; i < 4; ++i) {
    float inv = 1.0f / l[i];
    int mrow = q0 + ty * 4 + i;
    size_t base = (size_t)mrow * Hc + h * 64 + tx * 4;
    us4 hv, lv;
#pragma unroll
    for (int jj = 0; jj < 4; ++jj) {
      float v = oacc[i][jj] * inv;
      unsigned short hh, ll;
      split2(v, hh, ll);
      hv[jj] = hh; lv[jj] = ll;
    }
    *(us4*)&ctx_hi[base] = hv;
    *(us4*)&ctx_lo[base] = lv;
  }
}

// ---------------- router: softmax over 8 experts + top-2 + counts ----------------
__global__ __launch_bounds__(256) void k_router(const float* __restrict__ xf,
    const float* __restrict__ rw, int* __restrict__ topi,
    float* __restrict__ topw, int* __restrict__ counts) {
  int t = blockIdx.x;
  int tid = threadIdx.x;
  int e = tid >> 5, l = tid & 31;
  const float* xr = xf + (size_t)t * Hc;
  const float* we = rw + (size_t)e * Hc;
  float s = 0.f;
  for (int hh = l; hh < Hc; hh += 32) s += xr[hh] * we[hh];
  __shared__ float red[256];
  red[tid] = s; __syncthreads();
  for (int st = 16; st > 0; st >>= 1) {
    if (l < st) red[tid] += red[tid + st];
    __syncthreads();
  }
  if (tid == 0) {
    float lg[Ec], pr[Ec];
    float mx = -INFINITY;
    for (int k = 0; k < Ec; k++) { lg[k] = red[k * 32]; mx = fmaxf(mx, lg[k]); }
    float ps = 0.f;
    for (int k = 0; k < Ec; k++) { pr[k] = expf(lg[k] - mx); ps += pr[k]; }
    float inv = 1.0f / ps;
    for (int k = 0; k < Ec; k++) pr[k] *= inv;
    int i1 = 0;
    for (int k = 1; k < Ec; k++) if (pr[k] > pr[i1]) i1 = k;
    int i2 = (i1 == 0) ? 1 : 0;
    for (int k = 0; k < Ec; k++)
      if (k != i1 && pr[k] > pr[i2]) i2 = k;
    topi[2 * t] = i1; topi[2 * t + 1] = i2;
    topw[2 * t] = pr[i1]; topw[2 * t + 1] = pr[i2];
    atomicAdd(&counts[i1], 1);
    atomicAdd(&counts[i2], 1);
  }
}

__global__ void k_offs(const int* __restrict__ counts, int* __restrict__ offs) {
  int acc = 0;
  for (int e = 0; e < Ec; e++) { offs[e] = acc; acc += counts[e]; }
}

__global__ __launch_bounds__(256) void k_scatter(const int* __restrict__ topi,
    const float* __restrict__ topw, const int* __restrict__ offs,
    int* __restrict__ cursor, int* __restrict__ elist,
    float* __restrict__ ecoef) {
  int t = blockIdx.x * 256 + threadIdx.x;
  if (t >= Sc) return;
#pragma unroll
  for (int s = 0; s < Kc; s++) {
    int e = topi[2 * t + s];
    int p = atomicAdd(&cursor[e], 1);
    int gslot = offs[e] + p;
    elist[gslot] = t;
    ecoef[gslot] = topw[2 * t + s];
  }
}

extern "C" void kernel_launch(void* const* d_in, const int* in_sizes, int n_in,
                              void* d_out, int out_size, void* d_ws, size_t ws_size,
                              hipStream_t stream) {
  const int*   idx   = (const int*)d_in[0];
  const float* tok   = (const float*)d_in[1];
  const float* pos   = (const float*)d_in[2];
  const float* ln1g  = (const float*)d_in[3];
  const float* ln1b  = (const float*)d_in[4];
  const float* wqkv  = (const float*)d_in[5];
  const float* bqkv  = (const float*)d_in[6];
  const float* wo    = (const float*)d_in[7];
  const float* bo    = (const float*)d_in[8];
  const float* ln2g  = (const float*)d_in[9];
  const float* ln2b  = (const float*)d_in[10];
  const float* rw    = (const float*)d_in[11];
  const float* w1    = (const float*)d_in[12];
  const float* w2    = (const float*)d_in[13];
  const float* lnfg  = (const float*)d_in[14];
  const float* lnfb  = (const float*)d_in[15];

  float* ws   = (float*)d_ws;
  float* x    = ws;                    // Sc*Hc
  float* lnb  = x + Sc * Hc;           // Sc*Hc
  float* qkv  = lnb + Sc * Hc;         // Sc*3*Hc
  float* topw  = qkv + Sc * 3 * Hc;    // Sc*Kc
  float* ecoef = topw + Sc * Kc;       // Sc*Kc
  int* topi    = (int*)(ecoef + Sc * Kc);  // Sc*Kc
  int* elist   = topi + Sc * Kc;           // Sc*Kc
  int* counts  = elist + Sc * Kc;          // Ec
  int* cursor  = counts + Ec;              // Ec
  int* offs    = cursor + Ec;              // Ec
  unsigned short* lnb_hi = (unsigned short*)(offs + Ec);   // Sc*Hc ushort
  unsigned short* lnb_lo = lnb_hi + (size_t)Sc * Hc;       // Sc*Hc ushort

  // d_out scratch (262 MB): h1 bf16 planes + ctx bf16 planes; all consumed
  // before the LM head overwrites d_out with logits.
  unsigned short* h1_hi  = (unsigned short*)d_out;                 // Sc*Kc*FFc
  unsigned short* h1_lo  = h1_hi + (size_t)Sc * Kc * FFc;
  unsigned short* ctx_hi = h1_lo + (size_t)Sc * Kc * FFc;          // Sc*Hc
  unsigned short* ctx_lo = ctx_hi + (size_t)Sc * Hc;

  k_embed<<<Sc, 256, 0, stream>>>(idx, tok, pos, x);
  for (int l = 0; l < Lc; l++) {
    k_ln<<<Sc, 256, 0, stream>>>(x, ln1g + l * Hc, ln1b + l * Hc, lnb, lnb_hi, lnb_lo);
    // QKV: [S,3H] = lnb @ wqkv^T + bqkv
    k_mfma_gemm<0, 0><<<dim3(Sc / BMg, 3 * Hc / BNg), 256, 0, stream>>>(
        lnb_hi, lnb_lo, wqkv + (size_t)l * 3 * Hc * Hc, bqkv + l * 3 * Hc,
        nullptr, qkv, nullptr, nullptr, nullptr, nullptr, nullptr, nullptr,
        Sc, 3 * Hc, Hc);
    k_attn_tile<<<dim3(Sc / 64, NHc), 256, 0, stream>>>(qkv, ctx_hi, ctx_lo);
    // WO: x += ctx @ wo^T + bo
    k_mfma_gemm<0, 0><<<dim3(Sc / BMg, Hc / BNg), 256, 0, stream>>>(
        ctx_hi, ctx_lo, wo + (size_t)l * Hc * Hc, bo + l * Hc, x, x,
        nullptr, nullptr, nullptr, nullptr, nullptr, nullptr, Sc, Hc, Hc);
    k_ln<<<Sc, 256, 0, stream>>>(x, ln2g + l * Hc, ln2b + l * Hc, lnb, lnb_hi, lnb_lo);
    hipMemsetAsync(counts, 0, 2 * Ec * sizeof(int), stream);
    k_router<<<Sc, 256, 0, stream>>>(lnb, rw + (size_t)l * Ec * Hc, topi, topw, counts);
    k_offs<<<1, 1, 0, stream>>>(counts, offs);
    k_scatter<<<Sc / 256, 256, 0, stream>>>(topi, topw, offs, cursor, elist, ecoef);
    // MoE GEMM1: h1 = gelu(gather(lnb) @ w1[e]); w1 is [K=H][N=FF]
    k_mfma_gemm<1, 1><<<dim3(Sc * Kc / BMg, FFc / BNg, Ec), 256, 0, stream>>>(
        lnb_hi, lnb_lo, w1 + (size_t)l * Ec * Hc * FFc, nullptr, nullptr,
        nullptr, h1_hi, h1_lo, elist, nullptr, counts, offs, Sc * Kc, FFc, Hc);
    // MoE GEMM2: x[tok] += coef * (h1 @ w2[e]); w2 is [K=FF][N=H]
    k_mfma_gemm<2, 1><<<dim3(Sc * Kc / BMg, Hc / BNg, Ec), 256, 0, stream>>>(
        h1_hi, h1_lo, w2 + (size_t)l * Ec * FFc * Hc, nullptr, nullptr,
        x, nullptr, nullptr, elist, ecoef, counts, offs, Sc * Kc, Hc, FFc);
  }
  k_ln<<<Sc, 256, 0, stream>>>(x, lnfg, lnfb, lnb, lnb_hi, lnb_lo);
  // LM head: logits = lnb @ tok^T
  k_mfma_gemm<0, 0><<<dim3(Sc / BMg, Vc / BNg), 256, 0, stream>>>(
      lnb_hi, lnb_lo, tok, nullptr, nullptr, (float*)d_out,
      nullptr, nullptr, nullptr, nullptr, nullptr, nullptr, Sc, Vc, Hc);
}